// Round 5
// baseline (287.883 us; speedup 1.0000x reference)
//
#include <hip/hip_runtime.h>
#include <cstdint>
#include <cstddef>

typedef short bf16x8 __attribute__((ext_vector_type(8)));
typedef float f32x4 __attribute__((ext_vector_type(4)));
typedef unsigned short u16x2 __attribute__((ext_vector_type(2)));
typedef unsigned short u16x4 __attribute__((ext_vector_type(4)));
typedef unsigned short u16x8 __attribute__((ext_vector_type(8)));

#define MFMA(a,b,c) __builtin_amdgcn_mfma_f32_16x16x32_bf16((a),(b),(c),0,0,0)

__device__ __forceinline__ unsigned short f2bf(float x){
  union { float f; unsigned u; } v; v.f = x;
  unsigned r = v.u + 0x7FFFu + ((v.u >> 16) & 1u);  // RNE
  return (unsigned short)(r >> 16);
}
__device__ __forceinline__ float bf2f(unsigned short b){
  union { unsigned u; float f; } v; v.u = ((unsigned)b) << 16;
  return v.f;
}
// load 8 consecutive fp32, convert to bf16x8 fragment
__device__ __forceinline__ bf16x8 cvtld8(const float* p){
  f32x4 a = *(const f32x4*)p;
  f32x4 b = *(const f32x4*)(p + 4);
  bf16x8 r;
  r[0]=(short)f2bf(a.x); r[1]=(short)f2bf(a.y);
  r[2]=(short)f2bf(a.z); r[3]=(short)f2bf(a.w);
  r[4]=(short)f2bf(b.x); r[5]=(short)f2bf(b.y);
  r[6]=(short)f2bf(b.z); r[7]=(short)f2bf(b.w);
  return r;
}

// ---------------- kernel 0: fp32 weights -> bf16 (wq,wk,wv,wg,wo) ----------
__global__ __launch_bounds__(256) void wcvt_kernel(
    const float* __restrict__ wq, const float* __restrict__ wk,
    const float* __restrict__ wv, const float* __restrict__ wg,
    const float* __restrict__ wo, unsigned short* __restrict__ dst)
{
  const int which = blockIdx.x >> 5;   // 32 blocks per 65536-elem matrix
  const float* s = (which==0)?wq:(which==1)?wk:(which==2)?wv:(which==3)?wg:wo;
  const int off = (blockIdx.x & 31) * 2048 + threadIdx.x * 8;
  f32x4 a = *(const f32x4*)(s + off);
  f32x4 b = *(const f32x4*)(s + off + 4);
  u16x8 r;
  r[0]=f2bf(a.x); r[1]=f2bf(a.y); r[2]=f2bf(a.z); r[3]=f2bf(a.w);
  r[4]=f2bf(b.x); r[5]=f2bf(b.y); r[6]=f2bf(b.z); r[7]=f2bf(b.w);
  *(u16x8*)(dst + (size_t)which*65536 + off) = r;
}

// ---------------- kernel 1: projections q,k,v(g) ---------------------------
// (verified round-0 version, unchanged)
__global__ __launch_bounds__(256,2) void proj_kernel(
    const float* __restrict__ q_x, const float* __restrict__ kv_x,
    const unsigned short* __restrict__ wb,   // bf16 weights: wq,wk,wv,wg,wo
    const float* __restrict__ bg,
    unsigned short* __restrict__ qws, unsigned short* __restrict__ kws,
    unsigned short* __restrict__ vTws, unsigned short* __restrict__ gws)
{
  const int tid = threadIdx.x;
  const int w = tid >> 6, lane = tid & 63;
  const int c = lane & 15, qd = lane >> 4;
  const int side = blockIdx.x >> 8;          // 256 row-blocks per side
  const int rb = (blockIdx.x & 255) * 16;    // 16 rows per WG
  const float* X = side ? kv_x : q_x;
  const unsigned short* W0 = wb + (size_t)(side ? 1 : 0) * 65536; // wk : wq
  const unsigned short* W1 = wb + (size_t)(side ? 2 : 3) * 65536; // wv : wg
  const int hdw = w * 64;                    // wave owns 64 output channels

  const f32x4 fz = {0.f,0.f,0.f,0.f};
  f32x4 acc[2][4];
  #pragma unroll
  for (int o=0;o<2;o++)
    #pragma unroll
    for (int mt=0;mt<4;mt++) acc[o][mt] = fz;

  #pragma unroll
  for (int ks = 0; ks < 8; ks++){
    const int ko = ks*32 + qd*8;
    bf16x8 bfrag = cvtld8(X + (size_t)(rb + c)*256 + ko);  // activation rows
    #pragma unroll
    for (int mt = 0; mt < 4; mt++){
      const int hd = hdw + mt*16 + c;
      bf16x8 a0 = *(const bf16x8*)(W0 + (size_t)hd*256 + ko);
      bf16x8 a1 = *(const bf16x8*)(W1 + (size_t)hd*256 + ko);
      acc[0][mt] = MFMA(a0, bfrag, acc[0][mt]);
      acc[1][mt] = MFMA(a1, bfrag, acc[1][mt]);
    }
  }

  const int row = rb + c;
  const int b = row >> 10, rr = row & 1023;
  #pragma unroll
  for (int mt = 0; mt < 4; mt++){
    const int hd0 = hdw + mt*16 + qd*4;
    const int h = hd0 >> 5, d0 = hd0 & 31;
    f32x4 v0 = acc[0][mt], v1 = acc[1][mt];
    if (side == 0){
      const float qs = 0.17677669529663687f;   // 1/sqrt(32)
      u16x4 oq = { f2bf(v0.x*qs), f2bf(v0.y*qs), f2bf(v0.z*qs), f2bf(v0.w*qs) };
      *(u16x4*)(qws + ((size_t)((b*8 + h)*1024 + rr))*32 + d0) = oq;
      f32x4 bg4 = *(const f32x4*)(bg + hd0);
      float g0 = 1.f/(1.f + exp2f(-1.44269504f*(v1.x + bg4.x)));
      float g1 = 1.f/(1.f + exp2f(-1.44269504f*(v1.y + bg4.y)));
      float g2 = 1.f/(1.f + exp2f(-1.44269504f*(v1.z + bg4.z)));
      float g3 = 1.f/(1.f + exp2f(-1.44269504f*(v1.w + bg4.w)));
      u16x4 og = { f2bf(g0), f2bf(g1), f2bf(g2), f2bf(g3) };
      *(u16x4*)(gws + ((size_t)((b*1024 + rr)*8 + h))*32 + d0) = og;
    } else {
      u16x4 ok = { f2bf(v0.x), f2bf(v0.y), f2bf(v0.z), f2bf(v0.w) };
      *(u16x4*)(kws + ((size_t)((b*8 + h)*1024 + rr))*32 + d0) = ok;
      size_t vb = ((size_t)((b*8 + h)*32 + d0))*1024 + rr;   // V^T scatter
      vTws[vb         ] = f2bf(v1.x);
      vTws[vb + 1024  ] = f2bf(v1.y);
      vTws[vb + 2048  ] = f2bf(v1.z);
      vTws[vb + 3072  ] = f2bf(v1.w);
    }
  }
}

// ---------------- kernel 2: flash attention, split-K in-WG ----------------
// One WG = 16 q-rows of one bh; its 4 waves each take one 256-key chunk
// (per-wave body instruction-identical to the verified round-3 chunk code).
// Partials (m, l, O) merge through LDS (reusing the pT region) with the
// exact split-softmax formula. Grid 2048 -> 4 WG/CU = 16 waves/CU, double
// round-3's TLP, with zero extra workspace.
__global__ __launch_bounds__(256,4) void attn_kernel(
    const float* __restrict__ pair_bias, const float* __restrict__ mask_bias,
    const unsigned short* __restrict__ qws, const unsigned short* __restrict__ kws,
    const unsigned short* __restrict__ vTws, const unsigned short* __restrict__ gws,
    unsigned short* __restrict__ ows)
{
  // 4 waves x 16 rows x 264 ushorts = 33792 B; merge partials reuse this
  // region after the first barrier (needs 8704 B).
  __shared__ __align__(16) unsigned short pT[4*4224];

  const int tid = threadIdx.x;
  const int w = tid >> 6, lane = tid & 63;
  const int c = lane & 15, qd = lane >> 4;
  // XCD swizzle (2048 % 8 == 0 -> bijective): 256 consecutive bids per XCD,
  // so the 64 WGs sharing each bh's K/V stay on one XCD's L2.
  const int bid = (int)((blockIdx.x & 7) * 256 + (blockIdx.x >> 3));
  const int bh = bid >> 6, qb16 = bid & 63;
  const int b  = bh >> 3, h = bh & 7;
  const int qrow = qb16*16 + c;        // 16 q-rows per WG, lane c indexes them
  const int k0 = w * 256;              // each wave owns one 256-key chunk

  const bf16x8 qf = *(const bf16x8*)(qws + ((size_t)bh*1024 + qrow)*32 + qd*8);
  const float* pbp = pair_bias + ((size_t)bh*1024 + qrow)*1024;
  const float* mbp = mask_bias + (size_t)b*1024;
  const unsigned short* kbp = kws  + (size_t)bh*32768;   // [key][32] bf16
  const unsigned short* vbp = vTws + (size_t)bh*32768;   // [d][1024] bf16
  unsigned short* pTw = pT + w*4224;          // 16 rows x 264 ushorts

  const f32x4 fz = {0.f,0.f,0.f,0.f};
  f32x4 accO0 = fz, accO1 = fz;

  // pass 1: S^T tiles (16 keys x 16 qrows each); depth-8 rotating
  // register prefetch keeps 16 loads in flight per wave.
  bf16x8 af[8]; f32x4 pb[8];
  #pragma unroll
  for (int i = 0; i < 8; i++){
    af[i] = *(const bf16x8*)(kbp + (size_t)(k0 + i*16 + c)*32 + qd*8);
    pb[i] = *(const f32x4*)(pbp + k0 + i*16 + qd*4);
  }
  f32x4 sf[16];
  float cmax = -3.0e38f;
  #pragma unroll
  for (int t = 0; t < 16; t++){
    const int r = t & 7;
    bf16x8 a   = af[r];
    f32x4 pbv  = pb[r];
    if (t < 8){
      af[r] = *(const bf16x8*)(kbp + (size_t)(k0 + (t+8)*16 + c)*32 + qd*8);
      pb[r] = *(const f32x4*)(pbp + k0 + (t+8)*16 + qd*4);
    }
    f32x4 mb = *(const f32x4*)(mbp + k0 + t*16 + qd*4);
    f32x4 s = MFMA(a, qf, fz);
    s = (s + pbv + mb) * 1.44269504f;
    sf[t] = s;
    cmax = fmaxf(cmax, fmaxf(fmaxf(s.x, s.y), fmaxf(s.z, s.w)));
  }
  // row (=col c) reduction across the 4 quads
  cmax = fmaxf(cmax, __shfl_xor(cmax, 16));
  cmax = fmaxf(cmax, __shfl_xor(cmax, 32));
  const float m_new = cmax;

  // issue all 16 V-fragment loads now; pass-2 VALU work hides their latency
  bf16x8 va0[8], va1[8];
  #pragma unroll
  for (int i = 0; i < 8; i++){
    va0[i] = *(const bf16x8*)(vbp + (size_t)c*1024      + k0 + i*32 + qd*8);
    va1[i] = *(const bf16x8*)(vbp + (size_t)(16+c)*1024 + k0 + i*32 + qd*8);
  }
  __builtin_amdgcn_sched_barrier(0);   // pin: V loads issue before pass 2

  // pass 2: exponentiate, pack P^T to LDS (per-wave buffer, no barrier)
  float rsum = 0.f;
  #pragma unroll
  for (int t = 0; t < 16; t++){
    f32x4 p;
    p.x = exp2f(sf[t].x - m_new);
    p.y = exp2f(sf[t].y - m_new);
    p.z = exp2f(sf[t].z - m_new);
    p.w = exp2f(sf[t].w - m_new);
    rsum += (p.x + p.y) + (p.z + p.w);
    u16x4 pk = { f2bf(p.x), f2bf(p.y), f2bf(p.z), f2bf(p.w) };
    *(u16x4*)(pTw + c*264 + t*16 + qd*4) = pk;
  }
  rsum += __shfl_xor(rsum, 16);
  rsum += __shfl_xor(rsum, 32);

  // PV: O^T(32xQ16) += V^T(32xKc) * P^T(Kcx16), V already in registers
  #pragma unroll
  for (int ks = 0; ks < 8; ks++){
    bf16x8 pf = *(const bf16x8*)(pTw + c*264 + ks*32 + qd*8);
    accO0 = MFMA(va0[ks], pf, accO0);
    accO1 = MFMA(va1[ks], pf, accO1);
  }

  // ---- cross-wave split-softmax merge through LDS (reuse pT region) ----
  __syncthreads();                       // all waves done with their pT
  float* mrg = (float*)pT;               // [0,64): m  [64,128): l  [128,...): O
  if (qd == 0){
    mrg[w*16 + c]      = m_new;
    mrg[64 + w*16 + c] = rsum;
  }
  {
    float* Ow = mrg + 128 + w*512 + c*32;
    *(f32x4*)(Ow + qd*4)      = accO0;
    *(f32x4*)(Ow + 16 + qd*4) = accO1;
  }
  __syncthreads();

  // 256 threads x 2 outputs: thread -> (q = tid>>4, d = (tid&15)*2)
  const int q  = tid >> 4;
  const int d  = (tid & 15) * 2;
  float m0 = mrg[q],      m1 = mrg[16 + q];
  float m2 = mrg[32 + q], m3 = mrg[48 + q];
  const float M = fmaxf(fmaxf(m0, m1), fmaxf(m2, m3));
  const float w0 = exp2f(m0 - M), w1 = exp2f(m1 - M);
  const float w2 = exp2f(m2 - M), w3 = exp2f(m3 - M);
  const float L = mrg[64 + q]*w0 + mrg[80 + q]*w1 + mrg[96 + q]*w2 + mrg[112 + q]*w3;
  const float* O0 = mrg + 128 + q*32 + d;
  float oa = O0[0]*w0 + O0[512]*w1 + O0[1024]*w2 + O0[1536]*w3;
  float ob = O0[1]*w0 + O0[513]*w1 + O0[1025]*w2 + O0[1537]*w3;
  const float invL = 1.0f / L;
  const size_t obase = (((size_t)b*1024 + qb16*16 + q)*8 + h)*32 + d;
  u16x2 g2 = *(const u16x2*)(gws + obase);
  u16x2 o2 = { f2bf(oa*invL*bf2f(g2[0])), f2bf(ob*invL*bf2f(g2[1])) };
  *(u16x2*)(ows + obase) = o2;
}

// ---------------- kernel 3: output projection -----------------------------
// (verified round-0 version, unchanged)
__global__ __launch_bounds__(256,2) void oproj_kernel(
    const unsigned short* __restrict__ ows, const unsigned short* __restrict__ wob,
    const float* __restrict__ bo, float* __restrict__ out)
{
  const int tid = threadIdx.x;
  const int w = tid >> 6, lane = tid & 63;
  const int c = lane & 15, qd = lane >> 4;
  const int row0 = blockIdx.x * 16;
  const int i0 = w * 64;

  const f32x4 fz = {0.f,0.f,0.f,0.f};
  f32x4 acc[4] = {fz, fz, fz, fz};
  #pragma unroll
  for (int ks = 0; ks < 8; ks++){
    const int ko = ks*32 + qd*8;
    bf16x8 bfrag = *(const bf16x8*)(ows + (size_t)(row0 + c)*256 + ko);
    #pragma unroll
    for (int mt = 0; mt < 4; mt++){
      bf16x8 afrag = *(const bf16x8*)(wob + (size_t)(i0 + mt*16 + c)*256 + ko);
      acc[mt] = MFMA(afrag, bfrag, acc[mt]);
    }
  }
  #pragma unroll
  for (int mt = 0; mt < 4; mt++){
    const int i = i0 + mt*16 + qd*4;
    f32x4 bo4 = *(const f32x4*)(bo + i);
    f32x4 r = acc[mt] + bo4;
    *(f32x4*)(out + (size_t)(row0 + c)*256 + i) = r;
  }
}

extern "C" void kernel_launch(void* const* d_in, const int* in_sizes, int n_in,
                              void* d_out, int out_size, void* d_ws, size_t ws_size,
                              hipStream_t stream) {
  const float* q_x       = (const float*)d_in[0];
  const float* kv_x      = (const float*)d_in[1];
  const float* mask_bias = (const float*)d_in[2];
  const float* pair_bias = (const float*)d_in[3];
  const float* wq        = (const float*)d_in[4];
  const float* wk        = (const float*)d_in[5];
  const float* wv        = (const float*)d_in[6];
  const float* wg        = (const float*)d_in[7];
  const float* bg        = (const float*)d_in[8];
  const float* wo        = (const float*)d_in[9];
  const float* bo        = (const float*)d_in[10];

  unsigned short* ws  = (unsigned short*)d_ws;
  unsigned short* qws  = ws;                       // [B,H,Q,D]  2MB
  unsigned short* kws  = ws + (1u<<20);            // [B,H,K,D]  2MB
  unsigned short* vTws = ws + 2*(1u<<20);          // [B,H,D,K]  2MB
  unsigned short* gws  = ws + 3*(1u<<20);          // [B,Q,H,D]  2MB
  unsigned short* ows  = ws + 4*(1u<<20);          // [B,Q,H*D]  2MB
  unsigned short* wb   = ws + 5*(1u<<20);          // 5 x 65536 bf16 weights

  wcvt_kernel<<<160, 256, 0, stream>>>(wq, wk, wv, wg, wo, wb);
  proj_kernel<<<512, 256, 0, stream>>>(q_x, kv_x, wb, bg, qws, kws, vTws, gws);
  attn_kernel<<<2048, 256, 0, stream>>>(pair_bias, mask_bias, qws, kws, vTws,
                                        gws, ows);
  oproj_kernel<<<256, 256, 0, stream>>>(ows, wb + 4*65536, bo, (float*)d_out);
}

// Round 6
// 259.398 us; speedup vs baseline: 1.1098x; 1.1098x over previous
//
#include <hip/hip_runtime.h>
#include <cstdint>
#include <cstddef>

typedef short bf16x8 __attribute__((ext_vector_type(8)));
typedef float f32x4 __attribute__((ext_vector_type(4)));
typedef unsigned short u16x2 __attribute__((ext_vector_type(2)));
typedef unsigned short u16x4 __attribute__((ext_vector_type(4)));
typedef unsigned short u16x8 __attribute__((ext_vector_type(8)));

#define MFMA(a,b,c) __builtin_amdgcn_mfma_f32_16x16x32_bf16((a),(b),(c),0,0,0)

__device__ __forceinline__ unsigned short f2bf(float x){
  union { float f; unsigned u; } v; v.f = x;
  unsigned r = v.u + 0x7FFFu + ((v.u >> 16) & 1u);  // RNE
  return (unsigned short)(r >> 16);
}
__device__ __forceinline__ float bf2f(unsigned short b){
  union { unsigned u; float f; } v; v.u = ((unsigned)b) << 16;
  return v.f;
}
// load 8 consecutive fp32, convert to bf16x8 fragment
__device__ __forceinline__ bf16x8 cvtld8(const float* p){
  f32x4 a = *(const f32x4*)p;
  f32x4 b = *(const f32x4*)(p + 4);
  bf16x8 r;
  r[0]=(short)f2bf(a.x); r[1]=(short)f2bf(a.y);
  r[2]=(short)f2bf(a.z); r[3]=(short)f2bf(a.w);
  r[4]=(short)f2bf(b.x); r[5]=(short)f2bf(b.y);
  r[6]=(short)f2bf(b.z); r[7]=(short)f2bf(b.w);
  return r;
}

// ---------------- kernel 0: fp32 weights -> bf16 (wq,wk,wv,wg,wo) ----------
__global__ __launch_bounds__(256) void wcvt_kernel(
    const float* __restrict__ wq, const float* __restrict__ wk,
    const float* __restrict__ wv, const float* __restrict__ wg,
    const float* __restrict__ wo, unsigned short* __restrict__ dst)
{
  const int which = blockIdx.x >> 5;   // 32 blocks per 65536-elem matrix
  const float* s = (which==0)?wq:(which==1)?wk:(which==2)?wv:(which==3)?wg:wo;
  const int off = (blockIdx.x & 31) * 2048 + threadIdx.x * 8;
  f32x4 a = *(const f32x4*)(s + off);
  f32x4 b = *(const f32x4*)(s + off + 4);
  u16x8 r;
  r[0]=f2bf(a.x); r[1]=f2bf(a.y); r[2]=f2bf(a.z); r[3]=f2bf(a.w);
  r[4]=f2bf(b.x); r[5]=f2bf(b.y); r[6]=f2bf(b.z); r[7]=f2bf(b.w);
  *(u16x8*)(dst + (size_t)which*65536 + off) = r;
}

// ---------------- kernel 1: projections q,k,v(g) ---------------------------
// (verified round-0 version, unchanged)
__global__ __launch_bounds__(256,2) void proj_kernel(
    const float* __restrict__ q_x, const float* __restrict__ kv_x,
    const unsigned short* __restrict__ wb,   // bf16 weights: wq,wk,wv,wg,wo
    const float* __restrict__ bg,
    unsigned short* __restrict__ qws, unsigned short* __restrict__ kws,
    unsigned short* __restrict__ vTws, unsigned short* __restrict__ gws)
{
  const int tid = threadIdx.x;
  const int w = tid >> 6, lane = tid & 63;
  const int c = lane & 15, qd = lane >> 4;
  const int side = blockIdx.x >> 8;          // 256 row-blocks per side
  const int rb = (blockIdx.x & 255) * 16;    // 16 rows per WG
  const float* X = side ? kv_x : q_x;
  const unsigned short* W0 = wb + (size_t)(side ? 1 : 0) * 65536; // wk : wq
  const unsigned short* W1 = wb + (size_t)(side ? 2 : 3) * 65536; // wv : wg
  const int hdw = w * 64;                    // wave owns 64 output channels

  const f32x4 fz = {0.f,0.f,0.f,0.f};
  f32x4 acc[2][4];
  #pragma unroll
  for (int o=0;o<2;o++)
    #pragma unroll
    for (int mt=0;mt<4;mt++) acc[o][mt] = fz;

  #pragma unroll
  for (int ks = 0; ks < 8; ks++){
    const int ko = ks*32 + qd*8;
    bf16x8 bfrag = cvtld8(X + (size_t)(rb + c)*256 + ko);  // activation rows
    #pragma unroll
    for (int mt = 0; mt < 4; mt++){
      const int hd = hdw + mt*16 + c;
      bf16x8 a0 = *(const bf16x8*)(W0 + (size_t)hd*256 + ko);
      bf16x8 a1 = *(const bf16x8*)(W1 + (size_t)hd*256 + ko);
      acc[0][mt] = MFMA(a0, bfrag, acc[0][mt]);
      acc[1][mt] = MFMA(a1, bfrag, acc[1][mt]);
    }
  }

  const int row = rb + c;
  const int b = row >> 10, rr = row & 1023;
  #pragma unroll
  for (int mt = 0; mt < 4; mt++){
    const int hd0 = hdw + mt*16 + qd*4;
    const int h = hd0 >> 5, d0 = hd0 & 31;
    f32x4 v0 = acc[0][mt], v1 = acc[1][mt];
    if (side == 0){
      const float qs = 0.17677669529663687f;   // 1/sqrt(32)
      u16x4 oq = { f2bf(v0.x*qs), f2bf(v0.y*qs), f2bf(v0.z*qs), f2bf(v0.w*qs) };
      *(u16x4*)(qws + ((size_t)((b*8 + h)*1024 + rr))*32 + d0) = oq;
      f32x4 bg4 = *(const f32x4*)(bg + hd0);
      float g0 = 1.f/(1.f + exp2f(-1.44269504f*(v1.x + bg4.x)));
      float g1 = 1.f/(1.f + exp2f(-1.44269504f*(v1.y + bg4.y)));
      float g2 = 1.f/(1.f + exp2f(-1.44269504f*(v1.z + bg4.z)));
      float g3 = 1.f/(1.f + exp2f(-1.44269504f*(v1.w + bg4.w)));
      u16x4 og = { f2bf(g0), f2bf(g1), f2bf(g2), f2bf(g3) };
      *(u16x4*)(gws + ((size_t)((b*1024 + rr)*8 + h))*32 + d0) = og;
    } else {
      u16x4 ok = { f2bf(v0.x), f2bf(v0.y), f2bf(v0.z), f2bf(v0.w) };
      *(u16x4*)(kws + ((size_t)((b*8 + h)*1024 + rr))*32 + d0) = ok;
      size_t vb = ((size_t)((b*8 + h)*32 + d0))*1024 + rr;   // V^T scatter
      vTws[vb         ] = f2bf(v1.x);
      vTws[vb + 1024  ] = f2bf(v1.y);
      vTws[vb + 2048  ] = f2bf(v1.z);
      vTws[vb + 3072  ] = f2bf(v1.w);
    }
  }
}

// ---------------- kernel 2: flash attention, split-K in-WG ----------------
// One WG = 16 q-rows of one bh; its 4 waves each take one 256-key chunk.
// Round-5 structure (verified merge math) with the spill fix: NO explicit
// prefetch arrays — inline loads only, live set ~100 VGPR < 128 cap, so
// 4 WG/CU (16 waves/CU) comes without scratch traffic. TLP covers latency.
__global__ __launch_bounds__(256,4) void attn_kernel(
    const float* __restrict__ pair_bias, const float* __restrict__ mask_bias,
    const unsigned short* __restrict__ qws, const unsigned short* __restrict__ kws,
    const unsigned short* __restrict__ vTws, const unsigned short* __restrict__ gws,
    unsigned short* __restrict__ ows)
{
  // 4 waves x 16 rows x 264 ushorts = 33792 B; merge partials reuse this
  // region after the first barrier (needs 9728 B at stride 36).
  __shared__ __align__(16) unsigned short pT[4*4224];

  const int tid = threadIdx.x;
  const int w = tid >> 6, lane = tid & 63;
  const int c = lane & 15, qd = lane >> 4;
  // XCD swizzle (2048 % 8 == 0 -> bijective): 256 consecutive bids per XCD,
  // so the 64 WGs sharing each bh's K/V stay on one XCD's L2.
  const int bid = (int)((blockIdx.x & 7) * 256 + (blockIdx.x >> 3));
  const int bh = bid >> 6, qb16 = bid & 63;
  const int b  = bh >> 3, h = bh & 7;
  const int qrow = qb16*16 + c;        // 16 q-rows per WG, lane c indexes them
  const int k0 = w * 256;              // each wave owns one 256-key chunk

  const bf16x8 qf = *(const bf16x8*)(qws + ((size_t)bh*1024 + qrow)*32 + qd*8);
  const float* pbp = pair_bias + ((size_t)bh*1024 + qrow)*1024;
  const float* mbp = mask_bias + (size_t)b*1024;
  const unsigned short* kbp = kws  + (size_t)bh*32768;   // [key][32] bf16
  const unsigned short* vbp = vTws + (size_t)bh*32768;   // [d][1024] bf16
  unsigned short* pTw = pT + w*4224;          // 16 rows x 264 ushorts

  const f32x4 fz = {0.f,0.f,0.f,0.f};
  f32x4 accO0 = fz, accO1 = fz;

  // pass 1: S^T tiles (16 keys x 16 qrows each), inline loads; 16 waves/CU
  // of TLP hide the K/pb/mb latency.
  f32x4 sf[16];
  float cmax = -3.0e38f;
  #pragma unroll
  for (int t = 0; t < 16; t++){
    bf16x8 af = *(const bf16x8*)(kbp + (size_t)(k0 + t*16 + c)*32 + qd*8);
    f32x4 s = MFMA(af, qf, fz);
    f32x4 pb = *(const f32x4*)(pbp + k0 + t*16 + qd*4);
    f32x4 mb = *(const f32x4*)(mbp + k0 + t*16 + qd*4);
    s = (s + pb + mb) * 1.44269504f;
    sf[t] = s;
    cmax = fmaxf(cmax, fmaxf(fmaxf(s.x, s.y), fmaxf(s.z, s.w)));
  }
  // row (=col c) reduction across the 4 quads
  cmax = fmaxf(cmax, __shfl_xor(cmax, 16));
  cmax = fmaxf(cmax, __shfl_xor(cmax, 32));
  const float m_new = cmax;

  // pass 2: exponentiate, pack P^T to LDS (per-wave buffer, no barrier)
  float rsum = 0.f;
  #pragma unroll
  for (int t = 0; t < 16; t++){
    f32x4 p;
    p.x = exp2f(sf[t].x - m_new);
    p.y = exp2f(sf[t].y - m_new);
    p.z = exp2f(sf[t].z - m_new);
    p.w = exp2f(sf[t].w - m_new);
    rsum += (p.x + p.y) + (p.z + p.w);
    u16x4 pk = { f2bf(p.x), f2bf(p.y), f2bf(p.z), f2bf(p.w) };
    *(u16x4*)(pTw + c*264 + t*16 + qd*4) = pk;
  }
  rsum += __shfl_xor(rsum, 16);
  rsum += __shfl_xor(rsum, 32);

  // PV: O^T(32xQ16) += V^T(32xKc) * P^T(Kcx16), V inline from global (L2)
  #pragma unroll
  for (int ks = 0; ks < 8; ks++){
    bf16x8 pf = *(const bf16x8*)(pTw + c*264 + ks*32 + qd*8);
    bf16x8 v0 = *(const bf16x8*)(vbp + (size_t)c*1024      + k0 + ks*32 + qd*8);
    bf16x8 v1 = *(const bf16x8*)(vbp + (size_t)(16+c)*1024 + k0 + ks*32 + qd*8);
    accO0 = MFMA(v0, pf, accO0);
    accO1 = MFMA(v1, pf, accO1);
  }

  // ---- cross-wave split-softmax merge through LDS (reuse pT region) ----
  __syncthreads();                       // all waves done with their pT
  float* mrg = (float*)pT;               // [0,64): m  [64,128): l  [128,...): O
  if (qd == 0){
    mrg[w*16 + c]      = m_new;
    mrg[64 + w*16 + c] = rsum;
  }
  {
    float* Ow = mrg + 128 + w*576 + c*36;   // stride 36 floats: 16B-aligned,
    *(f32x4*)(Ow + qd*4)      = accO0;      // conflict-free across lanes
    *(f32x4*)(Ow + 16 + qd*4) = accO1;
  }
  __syncthreads();

  // 256 threads x 2 outputs: thread -> (q = tid>>4, d = (tid&15)*2)
  const int q  = tid >> 4;
  const int d  = (tid & 15) * 2;
  float m0 = mrg[q],      m1 = mrg[16 + q];
  float m2 = mrg[32 + q], m3 = mrg[48 + q];
  const float M = fmaxf(fmaxf(m0, m1), fmaxf(m2, m3));
  const float w0 = exp2f(m0 - M), w1 = exp2f(m1 - M);
  const float w2 = exp2f(m2 - M), w3 = exp2f(m3 - M);
  const float L = mrg[64 + q]*w0 + mrg[80 + q]*w1 + mrg[96 + q]*w2 + mrg[112 + q]*w3;
  const float* O0 = mrg + 128 + q*36 + d;
  float oa = O0[0]*w0 + O0[576]*w1 + O0[1152]*w2 + O0[1728]*w3;
  float ob = O0[1]*w0 + O0[577]*w1 + O0[1153]*w2 + O0[1729]*w3;
  const float invL = 1.0f / L;
  const size_t obase = (((size_t)b*1024 + qb16*16 + q)*8 + h)*32 + d;
  u16x2 g2 = *(const u16x2*)(gws + obase);
  u16x2 o2 = { f2bf(oa*invL*bf2f(g2[0])), f2bf(ob*invL*bf2f(g2[1])) };
  *(u16x2*)(ows + obase) = o2;
}

// ---------------- kernel 3: output projection -----------------------------
// (verified round-0 version, unchanged)
__global__ __launch_bounds__(256,2) void oproj_kernel(
    const unsigned short* __restrict__ ows, const unsigned short* __restrict__ wob,
    const float* __restrict__ bo, float* __restrict__ out)
{
  const int tid = threadIdx.x;
  const int w = tid >> 6, lane = tid & 63;
  const int c = lane & 15, qd = lane >> 4;
  const int row0 = blockIdx.x * 16;
  const int i0 = w * 64;

  const f32x4 fz = {0.f,0.f,0.f,0.f};
  f32x4 acc[4] = {fz, fz, fz, fz};
  #pragma unroll
  for (int ks = 0; ks < 8; ks++){
    const int ko = ks*32 + qd*8;
    bf16x8 bfrag = *(const bf16x8*)(ows + (size_t)(row0 + c)*256 + ko);
    #pragma unroll
    for (int mt = 0; mt < 4; mt++){
      bf16x8 afrag = *(const bf16x8*)(wob + (size_t)(i0 + mt*16 + c)*256 + ko);
      acc[mt] = MFMA(afrag, bfrag, acc[mt]);
    }
  }
  #pragma unroll
  for (int mt = 0; mt < 4; mt++){
    const int i = i0 + mt*16 + qd*4;
    f32x4 bo4 = *(const f32x4*)(bo + i);
    f32x4 r = acc[mt] + bo4;
    *(f32x4*)(out + (size_t)(row0 + c)*256 + i) = r;
  }
}

extern "C" void kernel_launch(void* const* d_in, const int* in_sizes, int n_in,
                              void* d_out, int out_size, void* d_ws, size_t ws_size,
                              hipStream_t stream) {
  const float* q_x       = (const float*)d_in[0];
  const float* kv_x      = (const float*)d_in[1];
  const float* mask_bias = (const float*)d_in[2];
  const float* pair_bias = (const float*)d_in[3];
  const float* wq        = (const float*)d_in[4];
  const float* wk        = (const float*)d_in[5];
  const float* wv        = (const float*)d_in[6];
  const float* wg        = (const float*)d_in[7];
  const float* bg        = (const float*)d_in[8];
  const float* wo        = (const float*)d_in[9];
  const float* bo        = (const float*)d_in[10];

  unsigned short* ws  = (unsigned short*)d_ws;
  unsigned short* qws  = ws;                       // [B,H,Q,D]  2MB
  unsigned short* kws  = ws + (1u<<20);            // [B,H,K,D]  2MB
  unsigned short* vTws = ws + 2*(1u<<20);          // [B,H,D,K]  2MB
  unsigned short* gws  = ws + 3*(1u<<20);          // [B,Q,H,D]  2MB
  unsigned short* ows  = ws + 4*(1u<<20);          // [B,Q,H*D]  2MB
  unsigned short* wb   = ws + 5*(1u<<20);          // 5 x 65536 bf16 weights

  wcvt_kernel<<<160, 256, 0, stream>>>(wq, wk, wv, wg, wo, wb);
  proj_kernel<<<512, 256, 0, stream>>>(q_x, kv_x, wb, bg, qws, kws, vTws, gws);
  attn_kernel<<<2048, 256, 0, stream>>>(pair_bias, mask_bias, qws, kws, vTws,
                                        gws, ows);
  oproj_kernel<<<256, 256, 0, stream>>>(ows, wb + 4*65536, bo, (float*)d_out);
}